// Round 22
// baseline (62.982 us; speedup 1.0000x reference)
//
#include <hip/hip_runtime.h>

#define BATCH 16
#define CH    64
#define LEN   4096
#define NCODE 1024
#define NPTS  (BATCH * LEN)   // 65536
#define NPART 512             // argmin blocks
#define UNITB 24576           // staging unit: 2 tiles (one per code-half) = 24KB

typedef float float2v __attribute__((ext_vector_type(2)));
typedef float float4v __attribute__((ext_vector_type(4)));
typedef short short8  __attribute__((ext_vector_type(8)));
typedef float f32x16  __attribute__((ext_vector_type(16)));
typedef unsigned int uint32;

// RNE float->bf16 (bit ops: no dependence on __hip_bfloat16 ABI)
__device__ __forceinline__ unsigned short f2bf(float f) {
    uint32 u = __builtin_bit_cast(uint32, f);
    u += 0x7fffu + ((u >> 16) & 1u);
    return (unsigned short)(u >> 16);
}
__device__ __forceinline__ float bf2f(unsigned short h) {
    uint32 u = ((uint32)h) << 16;
    return __builtin_bit_cast(float, u);
}

// ---------------------------------------------------------------------------
// Kernel 1 (prep): split codebook into bf16x3 MFMA A-fragments + w2 table.
// Step-unit contiguous layout: tile T -> Tp = T<16 ? 2T : 2(T-16)+1
//   cbf2[(Tp*12 + s*3 + sigma)*512 + lane*8 + i]
// 16 blocks x 256 thr, coalesced LDS-tiled staging. 4 threads per code.
// ---------------------------------------------------------------------------
__global__ __launch_bounds__(256) void vq_prep(const float* __restrict__ cb,
                                               short* __restrict__ cbf2,
                                               float* __restrict__ w2tab) {
    __shared__ float tile[64][65];
    __shared__ float s2p[4][64];
    const int k0 = blockIdx.x * 64;
    const int t  = threadIdx.x;
#pragma unroll
    for (int it = 0; it < 4; ++it) {
        int idx = it * 256 + t, row = idx >> 4, q = idx & 15;
        *(float4v*)&tile[row][q * 4] =
            *(const float4v*)&cb[(size_t)(k0 + row) * CH + q * 4];
    }
    __syncthreads();

    const int j  = t & 63;         // code within block
    const int cq = t >> 6;         // channel quarter == k-slice s
    const int k  = k0 + j, T = k >> 5, row = k & 31;
    const int Tp = (T < 16) ? (T * 2) : ((T - 16) * 2 + 1);
    float s2 = 0.f;
#pragma unroll
    for (int cc = 0; cc < 16; ++cc) {
        float xv = tile[j][cq * 16 + cc];
        s2 = fmaf(xv, xv, s2);
        unsigned short h1 = f2bf(xv); float f1 = bf2f(h1);
        float r1 = xv - f1;                     // exact residual
        unsigned short h2 = f2bf(r1); float f2 = bf2f(h2);
        float r2 = r1 - f2;                     // exact residual
        unsigned short h3 = f2bf(r2);
        int g = cc >> 3, i = cc & 7;
        int lane = g * 32 + row;
        size_t base = ((size_t)Tp * 12 + cq * 3) * 512 + lane * 8 + i;
        cbf2[base]        = (short)h1;
        cbf2[base + 512]  = (short)h2;
        cbf2[base + 1024] = (short)h3;
    }
    s2p[cq][j] = s2;
    __syncthreads();
    if (t < 64) {
        float s2t = ((s2p[0][t] + s2p[1][t]) + (s2p[2][t] + s2p[3][t]));
        int kk = k0 + t, TT = kk >> 5, rr = kk & 31;
        int hi = (rr >> 2) & 1, r = (rr & 3) + 4 * (rr >> 3);
        w2tab[((size_t)TT * 2 + hi) * 16 + r] = s2t;
    }
}

// per-tile epilogue: cost = w2 - 2*dot, running argmin (rows ascend in k).
__device__ __forceinline__ void epi(const f32x16& acc, int Tg, int g,
                                    float& bestc, int& bestk,
                                    const float* w2s) {
    const float4v* wt = (const float4v*)(w2s + ((size_t)Tg * 2 + g) * 16);
    float4v w0 = wt[0], w1 = wt[1], w2v = wt[2], w3 = wt[3];
    float wr[16] = {w0.x, w0.y, w0.z, w0.w, w1.x, w1.y, w1.z, w1.w,
                    w2v.x, w2v.y, w2v.z, w2v.w, w3.x, w3.y, w3.z, w3.w};
    int kbase = Tg * 32 + 4 * g;
#pragma unroll
    for (int r = 0; r < 16; ++r) {
        float cost = fmaf(-2.0f, acc[r], wr[r]);
        int kg = kbase + (r & 3) + 8 * (r >> 2);   // ascending in r
        if (cost < bestc) { bestc = cost; bestk = kg; }   // strict <
    }
}

// ---------------------------------------------------------------------------
// Kernel 2: MFMA argmin + fused gather, 2-slot LDS ring, dual acc chains.
// HINT MODEL (r19-r21): the waves-per-eu hint is emitted min=max and CAPS
// residency: (512,2) -> 1 block/CU (r21 occ 20%, VGPR 88 clean);
// wpe(4,4)/(512,4) -> 2 blocks but RA collapses to 64+spill under the
// 128-VGPR cap (r19/r20) even though the body fits in 88. Decouple:
// amdgpu_waves_per_eu(2, 8): min=2 keeps the 256-cap (clean 88-reg alloc),
// max=8 lifts the residency cap -> HW can place 2 blocks/CU = 16 waves.
// Body byte-identical to r21: depth-1 staging (T14), dual chains (A1
// retired early), raw s_barrier + lgkmcnt(0) (vmcnt prefetch in flight).
// ---------------------------------------------------------------------------
__global__ void __launch_bounds__(512)
__attribute__((amdgpu_waves_per_eu(2, 8)))
vq_argmin(const float*  __restrict__ x,
          const float*  __restrict__ cb,
          const short*  __restrict__ cbf2,
          const float*  __restrict__ w2tab,
          float*        __restrict__ quant,
          float*        __restrict__ idx_out,
          double*       __restrict__ partial) {
    __shared__ __attribute__((aligned(16))) char  ring[2 * UNITB];  // 48KB
    __shared__ __attribute__((aligned(16))) float w2s[NCODE];       // 4KB
    __shared__ float  smc[8][32];
    __shared__ int    smk[8][32];
    __shared__ int    fidx[128];
    __shared__ double sds[128];

    const int t   = threadIdx.x;
    const int l   = t & 63;
    const int w   = __builtin_amdgcn_readfirstlane(t >> 6);  // 0..7
    const int h2  = w >> 2;                 // code half
    const int ptl = (w & 3) * 32 + (l & 31);
    const int g   = l >> 5;                 // k-half group
    const int p0  = blockIdx.x * 128;
    const int b   = p0 >> 12;
    const int l0  = p0 & (LEN - 1);

    float* xs = (float*)ring;               // x tile overlays the ring (32KB)

    // ---- stage x tile (coalesced float4) + w2 table into LDS
#pragma unroll
    for (int it = 0; it < 4; ++it) {
        int fi = it * 512 + t, c = fi >> 5, p4 = fi & 31;
        *(float4v*)&xs[c * 128 + 4 * p4] =
            *(const float4v*)&x[((size_t)b * CH + c) * LEN + l0 + 4 * p4];
    }
    w2s[t]       = w2tab[t];
    w2s[t + 512] = w2tab[t + 512];
    __syncthreads();

    const float4v* gsrc = (const float4v*)cbf2;   // 1536 float4 per unit

    // issue unit0 loads now — latency hides under the B-frag build
    float4v u0a = gsrc[t], u0b = gsrc[512 + t], u0c = gsrc[1024 + t];

    // ---- build B-frags (x splits) ONCE + x2 partial over my 32 channels
    short8 B1[4], B2[4], B3[4];
    float x2p = 0.f;
#pragma unroll
    for (int s = 0; s < 4; ++s) {
#pragma unroll
        for (int i = 0; i < 8; ++i) {
            int c = s * 16 + g * 8 + i;     // same k-mapping as A frags
            float xv = xs[c * 128 + ptl];
            x2p = fmaf(xv, xv, x2p);
            unsigned short h1v = f2bf(xv); float f1 = bf2f(h1v);
            float r1 = xv - f1;
            unsigned short h2v = f2bf(r1); float f2 = bf2f(h2v);
            float r2 = r1 - f2;
            unsigned short h3v = f2bf(r2);
            B1[s][i] = (short)h1v; B2[s][i] = (short)h2v; B3[s][i] = (short)h3v;
        }
    }
    const float x2 = x2p + __shfl_xor(x2p, 32, 64);   // lane pairs share point
    __syncthreads();                        // xs dead; ring reuse begins

    // ---- prologue: write unit0 -> slot0 (auto vmcnt on u0*), publish
    {
        float4v* d = (float4v*)ring;
        d[t] = u0a; d[512 + t] = u0b; d[1024 + t] = u0c;
    }
    asm volatile("s_waitcnt lgkmcnt(0)" ::: "memory");
    __builtin_amdgcn_s_barrier();
    asm volatile("" ::: "memory");

    float bestc = 3.4e38f;
    int   bestk = 0;

    // one step: issue unit tt+1 loads -> compute tile tt from slot tt&1
    // (dual chains) -> ds_write unit tt+1 to slot (tt+1)&1 -> lgkm wait +
    // raw barrier (vmcnt prefetch never drained mid-loop).
#pragma unroll 2
    for (int tt = 0; tt < 16; ++tt) {
        float4v nx0, nx1, nx2;
        const bool pf = (tt + 1 < 16);
        if (pf) {
            const float4v* gs = gsrc + (size_t)(tt + 1) * 1536;
            nx0 = gs[t]; nx1 = gs[512 + t]; nx2 = gs[1024 + t];
        }
        const short* bp = (const short*)&ring[(tt & 1) * UNITB] + h2 * 6144;
        f32x16 acc1 = {0.f,0.f,0.f,0.f,0.f,0.f,0.f,0.f,
                       0.f,0.f,0.f,0.f,0.f,0.f,0.f,0.f};
        f32x16 acc2 = acc1;
#pragma unroll
        for (int s = 0; s < 4; ++s) {
            const short* fb = bp + (s * 3) * 512 + l * 8;
            short8 A1 = *(const short8*)(fb);
            short8 A2 = *(const short8*)(fb + 512);
            short8 A3 = *(const short8*)(fb + 1024);
            // dual chains alternate; A1 retired after 3rd use (liveness <=3)
            acc1 = __builtin_amdgcn_mfma_f32_32x32x16_bf16(A1, B1[s], acc1, 0, 0, 0);
            acc2 = __builtin_amdgcn_mfma_f32_32x32x16_bf16(A1, B2[s], acc2, 0, 0, 0);
            acc1 = __builtin_amdgcn_mfma_f32_32x32x16_bf16(A2, B1[s], acc1, 0, 0, 0);
            acc2 = __builtin_amdgcn_mfma_f32_32x32x16_bf16(A1, B3[s], acc2, 0, 0, 0);
            acc1 = __builtin_amdgcn_mfma_f32_32x32x16_bf16(A3, B1[s], acc1, 0, 0, 0);
            acc2 = __builtin_amdgcn_mfma_f32_32x32x16_bf16(A2, B2[s], acc2, 0, 0, 0);
        }
        f32x16 acc = acc1 + acc2;
        epi(acc, h2 * 16 + tt, g, bestc, bestk, w2s);
        if (pf) {
            float4v* d = (float4v*)&ring[((tt + 1) & 1) * UNITB];
            d[t] = nx0; d[512 + t] = nx1; d[1024 + t] = nx2;  // auto vmcnt wait
        }
        asm volatile("s_waitcnt lgkmcnt(0)" ::: "memory");
        __builtin_amdgcn_s_barrier();       // raw: no vmcnt drain
        asm volatile("" ::: "memory");
    }

    // ---- merge g-halves within wave (explicit smaller-k tie-break)
    {
        float ob = __shfl_xor(bestc, 32, 64);
        int   ok = __shfl_xor(bestk, 32, 64);
        if (ob < bestc || (ob == bestc && ok < bestk)) { bestc = ob; bestk = ok; }
    }
    // ---- merge the two code-half waves per point via LDS
    if (l < 32) { smc[w][l] = bestc; smk[w][l] = bestk; }
    __syncthreads();
    if (w < 4 && l < 32) {
        float ob = smc[w + 4][l];
        int   ok = smk[w + 4][l];
        if (ob < bestc || (ob == bestc && ok < bestk)) { bestc = ob; bestk = ok; }
        idx_out[p0 + w * 32 + l] = (float)bestk;
        fidx[w * 32 + l] = bestk;
        sds[w * 32 + l] = (double)x2 + (double)bestc;   // min d2 = x2 + (w2-2dot)
    }
    __syncthreads();

    // ---- fused gather: quant[b][c][l0+pt] = cb[fidx[pt]][c]
    {
        const int pt = t & 127;
        const int cq = t >> 7;           // 4 channel quarters x 16 ch
        const int k  = fidx[pt];
        const float4v* src = (const float4v*)(cb + (size_t)k * CH + cq * 16);
        float4v v0 = src[0], v1 = src[1], v2 = src[2], v3 = src[3];
        float vr[16] = {v0.x, v0.y, v0.z, v0.w, v1.x, v1.y, v1.z, v1.w,
                        v2.x, v2.y, v2.z, v2.w, v3.x, v3.y, v3.z, v3.w};
#pragma unroll
        for (int j = 0; j < 16; ++j) {
            int c = cq * 16 + j;
            quant[((size_t)b * CH + c) * LEN + l0 + pt] = vr[j];  // coalesced in pt
        }
    }

    if (t == 0) {
        double s = 0.0;
        for (int i = 0; i < 128; ++i) s += sds[i];
        partial[blockIdx.x] = s;
    }
}

// ---------------------------------------------------------------------------
// Kernel 3: final loss reduction over NPART per-block partials.
// ---------------------------------------------------------------------------
__global__ __launch_bounds__(256) void vq_loss(const double* __restrict__ partial,
                                               float*        __restrict__ losses) {
    __shared__ double sred[256];
    double v = 0.0;
#pragma unroll
    for (int i = 0; i < NPART / 256; ++i) v += partial[threadIdx.x + 256 * i];
    sred[threadIdx.x] = v;
    __syncthreads();
    for (int s = 128; s > 0; s >>= 1) {
        if (threadIdx.x < s) sred[threadIdx.x] += sred[threadIdx.x + s];
        __syncthreads();
    }
    if (threadIdx.x == 0) {
        float loss = (float)(sred[0] / (double)((size_t)NPTS * CH));
        losses[0] = loss;   // codebook_loss
        losses[1] = loss;   // commitment_loss (same value)
    }
}

// ---------------------------------------------------------------------------
extern "C" void kernel_launch(void* const* d_in, const int* in_sizes, int n_in,
                              void* d_out, int out_size, void* d_ws, size_t ws_size,
                              hipStream_t stream) {
    const float* x  = (const float*)d_in[0];   // (B, C, L)
    const float* cb = (const float*)d_in[1];   // (K, C)
    float* out = (float*)d_out;

    // d_out: [quant_out (B*C*L)] [codebook_loss] [commitment_loss] [indices (B*L)]
    float* quant_out = out;
    float* losses    = out + (size_t)BATCH * CH * LEN;
    float* idx_out   = losses + 2;

    // ws: [0,4KB) partials(512 dbl); [4KB,8KB) w2tab; [16KB,~400KB) cbf2 splits
    double* partial = (double*)d_ws;
    float*  w2tab   = (float*)((char*)d_ws + 4096);
    short*  cbf2    = (short*)((char*)d_ws + 16384);

    vq_prep<<<16, 256, 0, stream>>>(cb, cbf2, w2tab);
    vq_argmin<<<NPTS / 128, 512, 0, stream>>>(x, cb, cbf2, w2tab,
                                              quant_out, idx_out, partial);
    vq_loss<<<1, 256, 0, stream>>>(partial, losses);
}

// Round 23
// 61.779 us; speedup vs baseline: 1.0195x; 1.0195x over previous
//
#include <hip/hip_runtime.h>

#define BATCH 16
#define CH    64
#define LEN   4096
#define NCODE 1024
#define NPTS  (BATCH * LEN)   // 65536
#define NPART 512             // argmin blocks
#define UNITB 24576           // staging unit: 2 tiles (one per code-half) = 24KB

typedef float float2v __attribute__((ext_vector_type(2)));
typedef float float4v __attribute__((ext_vector_type(4)));
typedef short short8  __attribute__((ext_vector_type(8)));
typedef float f32x16  __attribute__((ext_vector_type(16)));
typedef unsigned int uint32;

// RNE float->bf16 (bit ops: no dependence on __hip_bfloat16 ABI)
__device__ __forceinline__ unsigned short f2bf(float f) {
    uint32 u = __builtin_bit_cast(uint32, f);
    u += 0x7fffu + ((u >> 16) & 1u);
    return (unsigned short)(u >> 16);
}
__device__ __forceinline__ float bf2f(unsigned short h) {
    uint32 u = ((uint32)h) << 16;
    return __builtin_bit_cast(float, u);
}

// ---------------------------------------------------------------------------
// Kernel 1 (prep): split codebook into bf16x3 MFMA A-fragments + w2 table.
// Step-unit contiguous layout: tile T -> Tp = T<16 ? 2T : 2(T-16)+1
//   cbf2[(Tp*12 + s*3 + sigma)*512 + lane*8 + i]
// 16 blocks x 256 thr, coalesced LDS-tiled staging. 4 threads per code.
// ---------------------------------------------------------------------------
__global__ __launch_bounds__(256) void vq_prep(const float* __restrict__ cb,
                                               short* __restrict__ cbf2,
                                               float* __restrict__ w2tab) {
    __shared__ float tile[64][65];
    __shared__ float s2p[4][64];
    const int k0 = blockIdx.x * 64;
    const int t  = threadIdx.x;
#pragma unroll
    for (int it = 0; it < 4; ++it) {
        int idx = it * 256 + t, row = idx >> 4, q = idx & 15;
        *(float4v*)&tile[row][q * 4] =
            *(const float4v*)&cb[(size_t)(k0 + row) * CH + q * 4];
    }
    __syncthreads();

    const int j  = t & 63;         // code within block
    const int cq = t >> 6;         // channel quarter == k-slice s
    const int k  = k0 + j, T = k >> 5, row = k & 31;
    const int Tp = (T < 16) ? (T * 2) : ((T - 16) * 2 + 1);
    float s2 = 0.f;
#pragma unroll
    for (int cc = 0; cc < 16; ++cc) {
        float xv = tile[j][cq * 16 + cc];
        s2 = fmaf(xv, xv, s2);
        unsigned short h1 = f2bf(xv); float f1 = bf2f(h1);
        float r1 = xv - f1;                     // exact residual
        unsigned short h2 = f2bf(r1); float f2 = bf2f(h2);
        float r2 = r1 - f2;                     // exact residual
        unsigned short h3 = f2bf(r2);
        int g = cc >> 3, i = cc & 7;
        int lane = g * 32 + row;
        size_t base = ((size_t)Tp * 12 + cq * 3) * 512 + lane * 8 + i;
        cbf2[base]        = (short)h1;
        cbf2[base + 512]  = (short)h2;
        cbf2[base + 1024] = (short)h3;
    }
    s2p[cq][j] = s2;
    __syncthreads();
    if (t < 64) {
        float s2t = ((s2p[0][t] + s2p[1][t]) + (s2p[2][t] + s2p[3][t]));
        int kk = k0 + t, TT = kk >> 5, rr = kk & 31;
        int hi = (rr >> 2) & 1, r = (rr & 3) + 4 * (rr >> 3);
        w2tab[((size_t)TT * 2 + hi) * 16 + r] = s2t;
    }
}

// per-tile epilogue: cost = w2 - 2*dot, running argmin (rows ascend in k).
__device__ __forceinline__ void epi(const f32x16& acc, int Tg, int g,
                                    float& bestc, int& bestk,
                                    const float* w2s) {
    const float4v* wt = (const float4v*)(w2s + ((size_t)Tg * 2 + g) * 16);
    float4v w0 = wt[0], w1 = wt[1], w2v = wt[2], w3 = wt[3];
    float wr[16] = {w0.x, w0.y, w0.z, w0.w, w1.x, w1.y, w1.z, w1.w,
                    w2v.x, w2v.y, w2v.z, w2v.w, w3.x, w3.y, w3.z, w3.w};
    int kbase = Tg * 32 + 4 * g;
#pragma unroll
    for (int r = 0; r < 16; ++r) {
        float cost = fmaf(-2.0f, acc[r], wr[r]);
        int kg = kbase + (r & 3) + 8 * (r >> 2);   // ascending in r
        if (cost < bestc) { bestc = cost; bestk = kg; }   // strict <
    }
}

// ---------------------------------------------------------------------------
// Kernel 2: MFMA argmin + fused gather, 2-slot LDS ring, SINGLE acc chain.
// RESIDENCY MODEL (r16-r22): VGPR=64-class kernels reach 2 blocks/CU (occ
// 32-40%); VGPR=88-class (dual chains, +32 AGPR) cap at 1 block (occ 20%).
// Dual chains bought 2x per-wave ILP but cost 2x residency — net wash
// (r18 single-chain = 53.9us remains best). This round: r21's lean frame
// (2-slot 56.8KB ring, lgkm-hygienic raw barriers, depth-1 T14 staging) +
// single chain (64-VGPR class) -> 2 blocks/CU x 8 waves = 4 waves/SIMD =
// 4 independent MFMA chains/SIMD (covers dep latency) AND 2x wave overlap
// of the LDS/VALU/barrier phases. + T5 s_setprio around the MFMA cluster
// (phase-split schedule with counted vmcnt = the regime where it pays).
// Math/k-mapping/tie-breaks byte-identical to r15-r22 passing kernels.
// ---------------------------------------------------------------------------
__global__ void __launch_bounds__(512, 2)
vq_argmin(const float*  __restrict__ x,
          const float*  __restrict__ cb,
          const short*  __restrict__ cbf2,
          const float*  __restrict__ w2tab,
          float*        __restrict__ quant,
          float*        __restrict__ idx_out,
          double*       __restrict__ partial) {
    __shared__ __attribute__((aligned(16))) char  ring[2 * UNITB];  // 48KB
    __shared__ __attribute__((aligned(16))) float w2s[NCODE];       // 4KB
    __shared__ float  smc[8][32];
    __shared__ int    smk[8][32];
    __shared__ int    fidx[128];
    __shared__ double sds[128];

    const int t   = threadIdx.x;
    const int l   = t & 63;
    const int w   = __builtin_amdgcn_readfirstlane(t >> 6);  // 0..7
    const int h2  = w >> 2;                 // code half
    const int ptl = (w & 3) * 32 + (l & 31);
    const int g   = l >> 5;                 // k-half group
    const int p0  = blockIdx.x * 128;
    const int b   = p0 >> 12;
    const int l0  = p0 & (LEN - 1);

    float* xs = (float*)ring;               // x tile overlays the ring (32KB)

    // ---- stage x tile (coalesced float4) + w2 table into LDS
#pragma unroll
    for (int it = 0; it < 4; ++it) {
        int fi = it * 512 + t, c = fi >> 5, p4 = fi & 31;
        *(float4v*)&xs[c * 128 + 4 * p4] =
            *(const float4v*)&x[((size_t)b * CH + c) * LEN + l0 + 4 * p4];
    }
    w2s[t]       = w2tab[t];
    w2s[t + 512] = w2tab[t + 512];
    __syncthreads();

    const float4v* gsrc = (const float4v*)cbf2;   // 1536 float4 per unit

    // issue unit0 loads now — latency hides under the B-frag build
    float4v u0a = gsrc[t], u0b = gsrc[512 + t], u0c = gsrc[1024 + t];

    // ---- build B-frags (x splits) ONCE + x2 partial over my 32 channels
    short8 B1[4], B2[4], B3[4];
    float x2p = 0.f;
#pragma unroll
    for (int s = 0; s < 4; ++s) {
#pragma unroll
        for (int i = 0; i < 8; ++i) {
            int c = s * 16 + g * 8 + i;     // same k-mapping as A frags
            float xv = xs[c * 128 + ptl];
            x2p = fmaf(xv, xv, x2p);
            unsigned short h1v = f2bf(xv); float f1 = bf2f(h1v);
            float r1 = xv - f1;
            unsigned short h2v = f2bf(r1); float f2 = bf2f(h2v);
            float r2 = r1 - f2;
            unsigned short h3v = f2bf(r2);
            B1[s][i] = (short)h1v; B2[s][i] = (short)h2v; B3[s][i] = (short)h3v;
        }
    }
    const float x2 = x2p + __shfl_xor(x2p, 32, 64);   // lane pairs share point
    __syncthreads();                        // xs dead; ring reuse begins

    // ---- prologue: write unit0 -> slot0 (auto vmcnt on u0*), publish
    {
        float4v* d = (float4v*)ring;
        d[t] = u0a; d[512 + t] = u0b; d[1024 + t] = u0c;
    }
    asm volatile("s_waitcnt lgkmcnt(0)" ::: "memory");
    __builtin_amdgcn_s_barrier();
    asm volatile("" ::: "memory");

    float bestc = 3.4e38f;
    int   bestk = 0;

    // one step: issue unit tt+1 loads -> compute tile tt from slot tt&1
    // (single chain, setprio'd) -> ds_write unit tt+1 to slot (tt+1)&1 ->
    // lgkm wait + raw barrier (vmcnt prefetch never drained mid-loop).
    for (int tt = 0; tt < 16; ++tt) {
        float4v nx0, nx1, nx2;
        const bool pf = (tt + 1 < 16);
        if (pf) {
            const float4v* gs = gsrc + (size_t)(tt + 1) * 1536;
            nx0 = gs[t]; nx1 = gs[512 + t]; nx2 = gs[1024 + t];
        }
        const short* bp = (const short*)&ring[(tt & 1) * UNITB] + h2 * 6144;
        f32x16 acc = {0.f,0.f,0.f,0.f,0.f,0.f,0.f,0.f,
                      0.f,0.f,0.f,0.f,0.f,0.f,0.f,0.f};
        __builtin_amdgcn_s_setprio(1);      // T5: favor this wave in MFMA phase
#pragma unroll
        for (int s = 0; s < 4; ++s) {
            const short* fb = bp + (s * 3) * 512 + l * 8;
            short8 A1 = *(const short8*)(fb);
            short8 A2 = *(const short8*)(fb + 512);
            short8 A3 = *(const short8*)(fb + 1024);
            // 6 split terms: 1, 2^-8, 2^-8, 2^-16, 2^-16, 2^-16
            acc = __builtin_amdgcn_mfma_f32_32x32x16_bf16(A1, B1[s], acc, 0, 0, 0);
            acc = __builtin_amdgcn_mfma_f32_32x32x16_bf16(A1, B2[s], acc, 0, 0, 0);
            acc = __builtin_amdgcn_mfma_f32_32x32x16_bf16(A2, B1[s], acc, 0, 0, 0);
            acc = __builtin_amdgcn_mfma_f32_32x32x16_bf16(A1, B3[s], acc, 0, 0, 0);
            acc = __builtin_amdgcn_mfma_f32_32x32x16_bf16(A3, B1[s], acc, 0, 0, 0);
            acc = __builtin_amdgcn_mfma_f32_32x32x16_bf16(A2, B2[s], acc, 0, 0, 0);
        }
        __builtin_amdgcn_s_setprio(0);
        epi(acc, h2 * 16 + tt, g, bestc, bestk, w2s);
        if (pf) {
            float4v* d = (float4v*)&ring[((tt + 1) & 1) * UNITB];
            d[t] = nx0; d[512 + t] = nx1; d[1024 + t] = nx2;  // auto vmcnt wait
        }
        asm volatile("s_waitcnt lgkmcnt(0)" ::: "memory");
        __builtin_amdgcn_s_barrier();       // raw: no vmcnt drain
        asm volatile("" ::: "memory");
    }

    // ---- merge g-halves within wave (explicit smaller-k tie-break)
    {
        float ob = __shfl_xor(bestc, 32, 64);
        int   ok = __shfl_xor(bestk, 32, 64);
        if (ob < bestc || (ob == bestc && ok < bestk)) { bestc = ob; bestk = ok; }
    }
    // ---- merge the two code-half waves per point via LDS
    if (l < 32) { smc[w][l] = bestc; smk[w][l] = bestk; }
    __syncthreads();
    if (w < 4 && l < 32) {
        float ob = smc[w + 4][l];
        int   ok = smk[w + 4][l];
        if (ob < bestc || (ob == bestc && ok < bestk)) { bestc = ob; bestk = ok; }
        idx_out[p0 + w * 32 + l] = (float)bestk;
        fidx[w * 32 + l] = bestk;
        sds[w * 32 + l] = (double)x2 + (double)bestc;   // min d2 = x2 + (w2-2dot)
    }
    __syncthreads();

    // ---- fused gather: quant[b][c][l0+pt] = cb[fidx[pt]][c]
    {
        const int pt = t & 127;
        const int cq = t >> 7;           // 4 channel quarters x 16 ch
        const int k  = fidx[pt];
        const float4v* src = (const float4v*)(cb + (size_t)k * CH + cq * 16);
        float4v v0 = src[0], v1 = src[1], v2 = src[2], v3 = src[3];
        float vr[16] = {v0.x, v0.y, v0.z, v0.w, v1.x, v1.y, v1.z, v1.w,
                        v2.x, v2.y, v2.z, v2.w, v3.x, v3.y, v3.z, v3.w};
#pragma unroll
        for (int j = 0; j < 16; ++j) {
            int c = cq * 16 + j;
            quant[((size_t)b * CH + c) * LEN + l0 + pt] = vr[j];  // coalesced in pt
        }
    }

    if (t == 0) {
        double s = 0.0;
        for (int i = 0; i < 128; ++i) s += sds[i];
        partial[blockIdx.x] = s;
    }
}

// ---------------------------------------------------------------------------
// Kernel 3: final loss reduction over NPART per-block partials.
// ---------------------------------------------------------------------------
__global__ __launch_bounds__(256) void vq_loss(const double* __restrict__ partial,
                                               float*        __restrict__ losses) {
    __shared__ double sred[256];
    double v = 0.0;
#pragma unroll
    for (int i = 0; i < NPART / 256; ++i) v += partial[threadIdx.x + 256 * i];
    sred[threadIdx.x] = v;
    __syncthreads();
    for (int s = 128; s > 0; s >>= 1) {
        if (threadIdx.x < s) sred[threadIdx.x] += sred[threadIdx.x + s];
        __syncthreads();
    }
    if (threadIdx.x == 0) {
        float loss = (float)(sred[0] / (double)((size_t)NPTS * CH));
        losses[0] = loss;   // codebook_loss
        losses[1] = loss;   // commitment_loss (same value)
    }
}

// ---------------------------------------------------------------------------
extern "C" void kernel_launch(void* const* d_in, const int* in_sizes, int n_in,
                              void* d_out, int out_size, void* d_ws, size_t ws_size,
                              hipStream_t stream) {
    const float* x  = (const float*)d_in[0];   // (B, C, L)
    const float* cb = (const float*)d_in[1];   // (K, C)
    float* out = (float*)d_out;

    // d_out: [quant_out (B*C*L)] [codebook_loss] [commitment_loss] [indices (B*L)]
    float* quant_out = out;
    float* losses    = out + (size_t)BATCH * CH * LEN;
    float* idx_out   = losses + 2;

    // ws: [0,4KB) partials(512 dbl); [4KB,8KB) w2tab; [16KB,~400KB) cbf2 splits
    double* partial = (double*)d_ws;
    float*  w2tab   = (float*)((char*)d_ws + 4096);
    short*  cbf2    = (short*)((char*)d_ws + 16384);

    vq_prep<<<16, 256, 0, stream>>>(cb, cbf2, w2tab);
    vq_argmin<<<NPTS / 128, 512, 0, stream>>>(x, cb, cbf2, w2tab,
                                              quant_out, idx_out, partial);
    vq_loss<<<1, 256, 0, stream>>>(partial, losses);
}